// Round 3
// baseline (4354.390 us; speedup 1.0000x reference)
//
#include <hip/hip_runtime.h>
#include <hip/hip_bf16.h>
#include <cstddef>

typedef __hip_bfloat16 bf16;

__device__ inline float ldv(const float* p) { return *p; }
__device__ inline float ldv(const bf16* p) { return __bfloat162float(*p); }
__device__ inline void stv(float* p, float v) { *p = v; }
__device__ inline void stv(bf16* p, float v) { *p = __float2bfloat16(v); }

// ---------------- graph preprocessing ----------------

__global__ void transpose_x_kernel(const float* __restrict__ x, float* __restrict__ xT, int N) {
    int idx = blockIdx.x * 256 + threadIdx.x;  // idx = t*N + n
    if (idx < 12 * N) {
        int t = idx / N, n = idx % N;
        const float* s = x + ((size_t)t * N + n) * 12;
        float* d = xT + (size_t)n * 144 + t * 12;
        #pragma unroll
        for (int k = 0; k < 12; k++) d[k] = s[k];
    }
}

__global__ void deg_kernel(const int* __restrict__ ei, int* __restrict__ deg, int E) {
    int e = blockIdx.x * 256 + threadIdx.x;
    if (e < E) atomicAdd(&deg[ei[E + e]], 1);
}

__global__ void scan_kernel(const int* __restrict__ deg, int* __restrict__ rs, int N) {
    __shared__ int part[1024];
    int tid = threadIdx.x;
    int chunk = (N + 1023) >> 10;
    int base = tid * chunk;
    int s = 0;
    for (int k = 0; k < chunk; k++) { int i = base + k; if (i < N) s += deg[i]; }
    part[tid] = s;
    __syncthreads();
    for (int off = 1; off < 1024; off <<= 1) {
        int v = (tid >= off) ? part[tid - off] : 0;
        __syncthreads();
        part[tid] += v;
        __syncthreads();
    }
    int run = part[tid] - s;  // exclusive prefix
    for (int k = 0; k < chunk; k++) {
        int i = base + k;
        if (i < N) { rs[i] = run; run += deg[i]; }
    }
    if (tid == 1023) rs[N] = part[1023];
}

__global__ void fill_kernel(const int* __restrict__ ei, const int* __restrict__ rs,
                            int* __restrict__ cur, int* __restrict__ csr, int E) {
    int e = blockIdx.x * 256 + threadIdx.x;
    if (e < E) {
        int d = ei[E + e];
        int pos = atomicAdd(&cur[d], 1);
        csr[rs[d] + pos] = ei[e];
    }
}

__global__ void transpose_kernel(const float* __restrict__ in, float* __restrict__ out, int r, int c) {
    int idx = blockIdx.x * 256 + threadIdx.x;
    if (idx < r * c) {
        int i = idx / c, j = idx % c;
        out[(size_t)j * r + i] = in[idx];
    }
}

__global__ void sentinel_kernel(float* out, int n) {
    int i = blockIdx.x * 256 + threadIdx.x;
    if (i < n) out[i] = 12345.0f;
}

// ---------------- conv1: CSR mean-aggregate (12 dims x 12 t) + fused GEMM + relu ----------------

template <typename ET>
__global__ __launch_bounds__(128) void conv1_kernel(
    const float* __restrict__ xT, const int* __restrict__ rs, const int* __restrict__ csr,
    const int* __restrict__ deg, const float* __restrict__ Wl, const float* __restrict__ Wr,
    const float* __restrict__ b, ET* __restrict__ emb1) {
    int n = blockIdx.x, tid = threadIdx.x;
    __shared__ float s_mean[144], s_x[144];
    __shared__ float s_wl[128 * 13], s_wr[128 * 13], s_b[128];
    for (int i = tid; i < 1536; i += 128) {
        int h = i / 12, j = i % 12;
        s_wl[h * 13 + j] = Wl[i];
        s_wr[h * 13 + j] = Wr[i];
    }
    s_b[tid] = b[tid];
    for (int i = tid; i < 144; i += 128) s_x[i] = xT[(size_t)n * 144 + i];
    int beg = rs[n], end = rs[n + 1];
    float a0 = 0.f, a1 = 0.f;
    for (int e = beg; e < end; e++) {
        int nbr = csr[e];
        const float* xr = xT + (size_t)nbr * 144;
        a0 += xr[tid];
        if (tid < 16) a1 += xr[128 + tid];
    }
    float inv = 1.0f / fmaxf((float)deg[n], 1.0f);
    s_mean[tid] = a0 * inv;
    if (tid < 16) s_mean[128 + tid] = a1 * inv;
    __syncthreads();
    for (int t = 0; t < 12; t++) {
        float o = s_b[tid];
        const float* m = s_mean + t * 12;
        const float* xv = s_x + t * 12;
        #pragma unroll
        for (int j = 0; j < 12; j++) o += m[j] * s_wl[tid * 13 + j] + xv[j] * s_wr[tid * 13 + j];
        stv(&emb1[(size_t)n * 1536 + t * 128 + tid], fmaxf(o, 0.0f));
    }
}

// ---------------- per-node temporal attention (T=12, H=128), optional sum over t ----------------

template <int SUM, typename ET>
__global__ __launch_bounds__(256) void attn_kernel(
    ET* __restrict__ data, const float* __restrict__ Wqt, const float* __restrict__ Wkt,
    const float* __restrict__ Wvt, const float* __restrict__ bq, const float* __restrict__ bk,
    const float* __restrict__ bv, float* __restrict__ outF) {
    int row = blockIdx.x, tid = threadIdx.x;
    __shared__ float h_s[12][129], q_s[12][129], k_s[12][129], v_s[12][129];
    __shared__ float w_s[12][13];
    ET* drow = data + (size_t)row * 1536;
    for (int i = tid; i < 1536; i += 256) h_s[i >> 7][i & 127] = ldv(&drow[i]);
    __syncthreads();
    const float scale = 0.08838834764831845f;  // 1/sqrt(128)
    int i = tid & 127, th = tid >> 7;
    #pragma unroll
    for (int r = 0; r < 6; r++) {
        int t = r * 2 + th;
        float aq = bq[i], ak = bk[i], av = bv[i];
        for (int j = 0; j < 128; j++) {
            float hv = h_s[t][j];
            aq += hv * Wqt[j * 128 + i];
            ak += hv * Wkt[j * 128 + i];
            av += hv * Wvt[j * 128 + i];
        }
        q_s[t][i] = aq * scale;
        k_s[t][i] = ak;
        v_s[t][i] = av;
    }
    __syncthreads();
    if (tid < 144) {
        int t = tid / 12, s = tid % 12;
        float acc = 0.f;
        for (int j = 0; j < 128; j++) acc += q_s[t][j] * k_s[s][j];
        w_s[t][s] = acc;
    }
    __syncthreads();
    if (tid < 12) {
        float m = -1e30f;
        #pragma unroll
        for (int s = 0; s < 12; s++) m = fmaxf(m, w_s[tid][s]);
        float sum = 0.f;
        #pragma unroll
        for (int s = 0; s < 12; s++) { float e = expf(w_s[tid][s] - m); w_s[tid][s] = e; sum += e; }
        float rinv = 1.0f / sum;
        #pragma unroll
        for (int s = 0; s < 12; s++) w_s[tid][s] *= rinv;
    }
    __syncthreads();
    if constexpr (SUM != 0) {
        __shared__ float psum[2][128];
        float acc = 0.f;
        #pragma unroll
        for (int r = 0; r < 6; r++) {
            int t = r * 2 + th;
            float o = 0.f;
            #pragma unroll
            for (int s = 0; s < 12; s++) o += w_s[t][s] * v_s[s][i];
            acc += o;
        }
        psum[th][i] = acc;
        __syncthreads();
        if (tid < 128) outF[(size_t)row * 128 + tid] = psum[0][tid] + psum[1][tid];
    } else {
        #pragma unroll
        for (int r = 0; r < 6; r++) {
            int t = r * 2 + th;
            float o = 0.f;
            #pragma unroll
            for (int s = 0; s < 12; s++) o += w_s[t][s] * v_s[s][i];
            stv(&drow[t * 128 + i], o);
        }
    }
}

// ---------------- conv2 restricted to selected nodes ----------------

template <typename ET>
__global__ __launch_bounds__(256) void conv2_kernel(
    const ET* __restrict__ emb1, const int* __restrict__ node_idx, const int* __restrict__ rs,
    const int* __restrict__ csr, const int* __restrict__ deg, const float* __restrict__ Wlt,
    const float* __restrict__ Wrt, const float* __restrict__ b2, float* __restrict__ emb2) {
    int bb = blockIdx.x, tid = threadIdx.x;
    int n = node_idx[bb];
    __shared__ float mean_s[12][129], hsel_s[12][129];
    for (int idx = tid; idx < 1536; idx += 256) hsel_s[idx >> 7][idx & 127] = ldv(&emb1[(size_t)n * 1536 + idx]);
    float acc[6] = {0.f, 0.f, 0.f, 0.f, 0.f, 0.f};
    int beg = rs[n], end = rs[n + 1];
    for (int e = beg; e < end; e++) {
        int nbr = csr[e];
        const ET* r = emb1 + (size_t)nbr * 1536;
        #pragma unroll
        for (int k = 0; k < 6; k++) acc[k] += ldv(&r[k * 256 + tid]);
    }
    float inv = 1.0f / fmaxf((float)deg[n], 1.0f);
    #pragma unroll
    for (int k = 0; k < 6; k++) {
        int idx = k * 256 + tid;
        mean_s[idx >> 7][idx & 127] = acc[k] * inv;
    }
    __syncthreads();
    int i = tid & 127, th = tid >> 7;
    #pragma unroll
    for (int r2 = 0; r2 < 6; r2++) {
        int t = r2 * 2 + th;
        float o = b2[i];
        for (int j = 0; j < 128; j++) o += mean_s[t][j] * Wlt[j * 128 + i] + hsel_s[t][j] * Wrt[j * 128 + i];
        emb2[(size_t)bb * 1536 + t * 128 + i] = fmaxf(o, 0.0f);
    }
}

// ---------------- MLP head ----------------

__global__ __launch_bounds__(256) void head_kernel(
    const float* __restrict__ embF, const float* __restrict__ apart, const float* __restrict__ fc1Wt,
    const float* __restrict__ fc1b, const float* __restrict__ fc2Wt, const float* __restrict__ fc2b,
    const float* __restrict__ fc3W, const float* __restrict__ fc3b, float* __restrict__ out) {
    int bb = blockIdx.x, tid = threadIdx.x;
    __shared__ float in_s[138], a1[256], a2[128], red[128];
    if (tid < 128) in_s[tid] = embF[(size_t)bb * 128 + tid];
    else if (tid < 138) in_s[tid] = apart[(size_t)bb * 10 + tid - 128];
    __syncthreads();
    float o = fc1b[tid];
    for (int j = 0; j < 138; j++) o += in_s[j] * fc1Wt[j * 256 + tid];
    a1[tid] = o >= 0.f ? o : 0.1f * o;
    __syncthreads();
    if (tid < 128) {
        float o2 = fc2b[tid];
        for (int j = 0; j < 256; j++) o2 += a1[j] * fc2Wt[j * 128 + tid];
        a2[tid] = o2 >= 0.f ? o2 : 0.05f * o2;
    }
    __syncthreads();
    if (tid < 128) red[tid] = a2[tid] * fc3W[tid];
    __syncthreads();
    for (int s = 64; s > 0; s >>= 1) {
        if (tid < s) red[tid] += red[tid + s];
        __syncthreads();
    }
    if (tid == 0) out[bb] = red[0] + fc3b[0];
}

// ---------------- launch ----------------

struct Plan {
    void* emb1;
    float *xT, *emb2, *embF;
    float *Wqt, *Wkt, *Wvt, *Wl2t, *Wr2t, *fc1Wt, *fc2Wt;
    int *deg, *rs, *cur, *csr;
    size_t total;
};

extern "C" void kernel_launch(void* const* d_in, const int* in_sizes, int n_in,
                              void* d_out, int out_size, void* d_ws, size_t ws_size,
                              hipStream_t stream) {
    const float* x    = (const float*)d_in[0];
    const int* ei     = (const int*)d_in[1];
    const int* nidx   = (const int*)d_in[2];
    const float* apart= (const float*)d_in[3];
    const float* c1Wl = (const float*)d_in[4];
    const float* c1Wr = (const float*)d_in[5];
    const float* c1b  = (const float*)d_in[6];
    const float* c2Wl = (const float*)d_in[7];
    const float* c2Wr = (const float*)d_in[8];
    const float* c2b  = (const float*)d_in[9];
    const float* Wq   = (const float*)d_in[10];
    const float* bq   = (const float*)d_in[11];
    const float* Wk   = (const float*)d_in[12];
    const float* bk   = (const float*)d_in[13];
    const float* Wv   = (const float*)d_in[14];
    const float* bv   = (const float*)d_in[15];
    const float* fc1W = (const float*)d_in[16];
    const float* fc1b = (const float*)d_in[17];
    const float* fc2W = (const float*)d_in[18];
    const float* fc2b = (const float*)d_in[19];
    const float* fc3W = (const float*)d_in[20];
    const float* fc3b = (const float*)d_in[21];

    int N = in_sizes[0] / 144;
    int E = in_sizes[1] / 2;
    int B = in_sizes[2];
    float* out = (float*)d_out;
    char* ws = (char*)d_ws;

    auto build = [&](size_t elemSz) -> Plan {
        Plan p;
        size_t off = 0;
        auto A = [&](size_t bytes) -> void* {
            void* q = ws + off;
            off = (off + bytes + 255) & ~(size_t)255;
            return q;
        };
        p.emb1 = A((size_t)N * 1536 * elemSz);
        size_t xtBytes = (size_t)N * 144 * 4;
        p.xT = (float*)A(xtBytes);
        size_t e2Bytes = (((size_t)B * 1536 * 4) + 255) & ~(size_t)255;
        size_t efBytes = (size_t)B * 128 * 4;
        if (e2Bytes + efBytes <= xtBytes) {  // alias onto xT (dead after conv1)
            p.emb2 = p.xT;
            p.embF = (float*)((char*)p.xT + e2Bytes);
        } else {
            p.emb2 = (float*)A((size_t)B * 1536 * 4);
            p.embF = (float*)A((size_t)B * 128 * 4);
        }
        p.Wqt  = (float*)A(16384 * 4);
        p.Wkt  = (float*)A(16384 * 4);
        p.Wvt  = (float*)A(16384 * 4);
        p.Wl2t = (float*)A(16384 * 4);
        p.Wr2t = (float*)A(16384 * 4);
        p.fc1Wt= (float*)A(138 * 256 * 4);
        p.fc2Wt= (float*)A(256 * 128 * 4);
        p.deg  = (int*)A((size_t)N * 4);
        p.rs   = (int*)A((size_t)(N + 1) * 4);
        p.cur  = (int*)A((size_t)N * 4);
        p.csr  = (int*)A((size_t)E * 4);
        p.total = off;
        return p;
    };

    Plan p = build(4);
    bool wide = true;
    if (p.total > ws_size) { p = build(2); wide = false; }
    if (p.total > ws_size) {
        // distinguishable sentinel: ws too small even for bf16 plan
        sentinel_kernel<<<(out_size + 255) / 256, 256, 0, stream>>>(out, out_size);
        return;
    }

    (void)hipMemsetAsync(p.deg, 0, (size_t)N * 4, stream);
    (void)hipMemsetAsync(p.cur, 0, (size_t)N * 4, stream);

    int eb = (E + 255) / 256;
    transpose_x_kernel<<<(12 * N + 255) / 256, 256, 0, stream>>>(x, p.xT, N);
    deg_kernel<<<eb, 256, 0, stream>>>(ei, p.deg, E);
    scan_kernel<<<1, 1024, 0, stream>>>(p.deg, p.rs, N);
    fill_kernel<<<eb, 256, 0, stream>>>(ei, p.rs, p.cur, p.csr, E);

    transpose_kernel<<<64, 256, 0, stream>>>(Wq, p.Wqt, 128, 128);
    transpose_kernel<<<64, 256, 0, stream>>>(Wk, p.Wkt, 128, 128);
    transpose_kernel<<<64, 256, 0, stream>>>(Wv, p.Wvt, 128, 128);
    transpose_kernel<<<64, 256, 0, stream>>>(c2Wl, p.Wl2t, 128, 128);
    transpose_kernel<<<64, 256, 0, stream>>>(c2Wr, p.Wr2t, 128, 128);
    transpose_kernel<<<(256 * 138 + 255) / 256, 256, 0, stream>>>(fc1W, p.fc1Wt, 256, 138);
    transpose_kernel<<<128, 256, 0, stream>>>(fc2W, p.fc2Wt, 128, 256);

    if (wide) {
        float* emb1 = (float*)p.emb1;
        conv1_kernel<float><<<N, 128, 0, stream>>>(p.xT, p.rs, p.csr, p.deg, c1Wl, c1Wr, c1b, emb1);
        attn_kernel<0, float><<<N, 256, 0, stream>>>(emb1, p.Wqt, p.Wkt, p.Wvt, bq, bk, bv, nullptr);
        conv2_kernel<float><<<B, 256, 0, stream>>>(emb1, nidx, p.rs, p.csr, p.deg, p.Wl2t, p.Wr2t, c2b, p.emb2);
    } else {
        bf16* emb1 = (bf16*)p.emb1;
        conv1_kernel<bf16><<<N, 128, 0, stream>>>(p.xT, p.rs, p.csr, p.deg, c1Wl, c1Wr, c1b, emb1);
        attn_kernel<0, bf16><<<N, 256, 0, stream>>>(emb1, p.Wqt, p.Wkt, p.Wvt, bq, bk, bv, nullptr);
        conv2_kernel<bf16><<<B, 256, 0, stream>>>(emb1, nidx, p.rs, p.csr, p.deg, p.Wl2t, p.Wr2t, c2b, p.emb2);
    }
    attn_kernel<1, float><<<B, 256, 0, stream>>>(p.emb2, p.Wqt, p.Wkt, p.Wvt, bq, bk, bv, p.embF);
    head_kernel<<<B, 256, 0, stream>>>(p.embF, apart, p.fc1Wt, fc1b, p.fc2Wt, fc2b, fc3W, fc3b, out);
}

// Round 4
// 1235.253 us; speedup vs baseline: 3.5251x; 3.5251x over previous
//
#include <hip/hip_runtime.h>
#include <hip/hip_bf16.h>
#include <cstddef>
#include <cstdint>
#include <cmath>

typedef __hip_bfloat16 bf16;
typedef __attribute__((ext_vector_type(8))) short bf16x8v;  // MFMA A/B frag (8 bf16)
typedef __attribute__((ext_vector_type(4))) float f32x4;    // MFMA C/D frag

__device__ inline float ldv(const bf16* p) { return __bfloat162float(*p); }
__device__ inline void stv(bf16* p, float v) { *p = __float2bfloat16(v); }

__device__ inline unsigned short f2bf(float x) {  // RNE
    uint32_t u = __float_as_uint(x);
    uint32_t r = (u + 0x7fffu + ((u >> 16) & 1u)) >> 16;
    return (unsigned short)r;
}

__device__ inline void unpack8(bf16x8v v, float* f) {
    union { bf16x8v v8; uint32_t u[4]; } cv; cv.v8 = v;
    #pragma unroll
    for (int d = 0; d < 4; d++) {
        uint32_t w = cv.u[d];
        f[2 * d]     = __uint_as_float(w << 16);
        f[2 * d + 1] = __uint_as_float(w & 0xffff0000u);
    }
}

// ---------------- graph preprocessing ----------------

__global__ void transpose_x_kernel(const float* __restrict__ x, float* __restrict__ xT, int N) {
    int idx = blockIdx.x * 256 + threadIdx.x;  // idx = t*N + n
    if (idx < 12 * N) {
        int t = idx / N, n = idx % N;
        const float* s = x + ((size_t)t * N + n) * 12;
        float* d = xT + (size_t)n * 144 + t * 12;
        #pragma unroll
        for (int k = 0; k < 12; k++) d[k] = s[k];
    }
}

__global__ void deg_kernel(const int* __restrict__ ei, int* __restrict__ deg, int E) {
    int e = blockIdx.x * 256 + threadIdx.x;
    if (e < E) atomicAdd(&deg[ei[E + e]], 1);
}

__global__ void scan_kernel(const int* __restrict__ deg, int* __restrict__ rs, int N) {
    __shared__ int part[1024];
    int tid = threadIdx.x;
    int chunk = (N + 1023) >> 10;
    int base = tid * chunk;
    int s = 0;
    for (int k = 0; k < chunk; k++) { int i = base + k; if (i < N) s += deg[i]; }
    part[tid] = s;
    __syncthreads();
    for (int off = 1; off < 1024; off <<= 1) {
        int v = (tid >= off) ? part[tid - off] : 0;
        __syncthreads();
        part[tid] += v;
        __syncthreads();
    }
    int run = part[tid] - s;
    for (int k = 0; k < chunk; k++) {
        int i = base + k;
        if (i < N) { rs[i] = run; run += deg[i]; }
    }
    if (tid == 1023) rs[N] = part[1023];
}

__global__ void fill_kernel(const int* __restrict__ ei, const int* __restrict__ rs,
                            int* __restrict__ cur, int* __restrict__ csr, int E) {
    int e = blockIdx.x * 256 + threadIdx.x;
    if (e < E) {
        int d = ei[E + e];
        int pos = atomicAdd(&cur[d], 1);
        csr[rs[d] + pos] = ei[e];
    }
}

__global__ void transpose_kernel(const float* __restrict__ in, float* __restrict__ out, int r, int c) {
    int idx = blockIdx.x * 256 + threadIdx.x;
    if (idx < r * c) {
        int i = idx / c, j = idx % c;
        out[(size_t)j * r + i] = in[idx];
    }
}

// pack Wq/Wk/Wv into MFMA B-fragment order: [pass][kc(4)][nt(8)][lane(64)][i(8)]
// B elem i of lane l: col = nt*16 + (l&15), j = kc*32 + (l>>4)*8 + i
__global__ void pack_qkv_kernel(const float* __restrict__ Wq, const float* __restrict__ Wk,
                                const float* __restrict__ Wv, unsigned short* __restrict__ out) {
    int idx = blockIdx.x * 256 + threadIdx.x;
    if (idx >= 3 * 16384) return;
    int p = idx >> 14, rem = idx & 16383;
    int kc = rem >> 12, rem2 = rem & 4095;
    int nt = rem2 >> 9, li = rem2 & 511;
    int l = li >> 3, i = li & 7;
    int col = nt * 16 + (l & 15);
    int j = kc * 32 + (l >> 4) * 8 + i;
    const float* W = (p == 0) ? Wq : (p == 1) ? Wk : Wv;
    out[idx] = f2bf(W[col * 128 + j]);
}

__global__ void sentinel_kernel(float* out, int n) {
    int i = blockIdx.x * 256 + threadIdx.x;
    if (i < n) out[i] = 12345.0f;
}

// ---------------- conv1: CSR mean-aggregate + fused GEMM + relu (emb1 bf16) ----------------

__global__ __launch_bounds__(128) void conv1_kernel(
    const float* __restrict__ xT, const int* __restrict__ rs, const int* __restrict__ csr,
    const int* __restrict__ deg, const float* __restrict__ Wl, const float* __restrict__ Wr,
    const float* __restrict__ b, bf16* __restrict__ emb1) {
    int n = blockIdx.x, tid = threadIdx.x;
    __shared__ float s_mean[144], s_x[144];
    __shared__ float s_wl[128 * 13], s_wr[128 * 13], s_b[128];
    for (int i = tid; i < 1536; i += 128) {
        int h = i / 12, j = i % 12;
        s_wl[h * 13 + j] = Wl[i];
        s_wr[h * 13 + j] = Wr[i];
    }
    s_b[tid] = b[tid];
    for (int i = tid; i < 144; i += 128) s_x[i] = xT[(size_t)n * 144 + i];
    int beg = rs[n], end = rs[n + 1];
    float a0 = 0.f, a1 = 0.f;
    for (int e = beg; e < end; e++) {
        int nbr = csr[e];
        const float* xr = xT + (size_t)nbr * 144;
        a0 += xr[tid];
        if (tid < 16) a1 += xr[128 + tid];
    }
    float inv = 1.0f / fmaxf((float)deg[n], 1.0f);
    s_mean[tid] = a0 * inv;
    if (tid < 16) s_mean[128 + tid] = a1 * inv;
    __syncthreads();
    for (int t = 0; t < 12; t++) {
        float o = s_b[tid];
        const float* m = s_mean + t * 12;
        const float* xv = s_x + t * 12;
        #pragma unroll
        for (int j = 0; j < 12; j++) o += m[j] * s_wl[tid * 13 + j] + xv[j] * s_wr[tid * 13 + j];
        stv(&emb1[(size_t)n * 1536 + t * 128 + tid], fmaxf(o, 0.0f));
    }
}

// ---------------- fused MFMA attention: 1 wave = 4 nodes (48 rows) ----------------
// io: bf16 rows [R][128]. SUM=0: write attn output in-place. SUM=1: write sum over t to outF.

template <int SUM>
__global__ __launch_bounds__(64) void mfma_attn_kernel(
    unsigned short* io, const unsigned short* __restrict__ Bpack,
    const float* __restrict__ bq, const float* __restrict__ bk, const float* __restrict__ bv,
    float* __restrict__ outF, int totalRows) {
    int l = threadIdx.x;
    int g = l >> 4, lam = l & 15;
    int baseRow = blockIdx.x * 48;

    __shared__ unsigned short qL[4][12][136];
    __shared__ unsigned short kL[4][12][136];
    __shared__ unsigned short vL[4][12][136];

    // ---- load A fragments (rows of h), rt in 0..2, kc in 0..3 ----
    bf16x8v afrag[3][4];
    #pragma unroll
    for (int rt = 0; rt < 3; rt++) {
        int row = baseRow + rt * 16 + lam;
        if (row > totalRows - 1) row = totalRows - 1;
        #pragma unroll
        for (int kc = 0; kc < 4; kc++) {
            afrag[rt][kc] = *(const bf16x8v*)(io + (size_t)row * 128 + kc * 32 + g * 8);
        }
    }

    const float qscale = 0.08838834764831845f;  // 1/sqrt(128)

    // ---- 3 projection passes (q, k, v) via MFMA ----
    #pragma unroll
    for (int p = 0; p < 3; p++) {
        f32x4 acc[3][8];
        #pragma unroll
        for (int rt = 0; rt < 3; rt++)
            #pragma unroll
            for (int nt = 0; nt < 8; nt++) acc[rt][nt] = (f32x4){0.f, 0.f, 0.f, 0.f};
        const unsigned short* Bp = Bpack + p * 16384;
        #pragma unroll
        for (int kc = 0; kc < 4; kc++) {
            #pragma unroll
            for (int nt = 0; nt < 8; nt++) {
                bf16x8v bfrag = *(const bf16x8v*)(Bp + (kc * 8 + nt) * 512 + l * 8);
                #pragma unroll
                for (int rt = 0; rt < 3; rt++)
                    acc[rt][nt] = __builtin_amdgcn_mfma_f32_16x16x32_bf16(afrag[rt][kc], bfrag, acc[rt][nt], 0, 0, 0);
            }
        }
        const float* bias = (p == 0) ? bq : (p == 1) ? bk : bv;
        #pragma unroll
        for (int nt = 0; nt < 8; nt++) {
            float bval = bias[nt * 16 + lam];
            #pragma unroll
            for (int rt = 0; rt < 3; rt++) {
                int rstart = 16 * rt + 4 * g;        // 4-row block, always within one node
                int m = rstart / 12;
                int tbase = rstart - 12 * m;
                #pragma unroll
                for (int r = 0; r < 4; r++) {
                    float val = acc[rt][nt][r] + bval;
                    if (p == 0) val *= qscale;
                    unsigned short hv = f2bf(val);
                    int t = tbase + r, c = nt * 16 + lam;
                    if (p == 0) qL[m][t][c] = hv;
                    else if (p == 1) kL[m][t][c] = hv;
                    else vL[m][t][c] = hv;
                }
            }
        }
    }
    __syncthreads();

    // ---- QK^T + softmax: lane lam = t (12 active per 16-lane group = node g) ----
    float pr[12];
    if (lam < 12) {
        float accS[12];
        #pragma unroll
        for (int s = 0; s < 12; s++) accS[s] = 0.f;
        for (int ch = 0; ch < 16; ch++) {
            bf16x8v qv = *(const bf16x8v*)&qL[g][lam][ch * 8];
            float qf[8]; unpack8(qv, qf);
            #pragma unroll
            for (int s = 0; s < 12; s++) {
                bf16x8v kv = *(const bf16x8v*)&kL[g][s][ch * 8];
                float kf[8]; unpack8(kv, kf);
                #pragma unroll
                for (int i = 0; i < 8; i++) accS[s] += qf[i] * kf[i];
            }
        }
        float mx = -1e30f;
        #pragma unroll
        for (int s = 0; s < 12; s++) mx = fmaxf(mx, accS[s]);
        float sum = 0.f;
        #pragma unroll
        for (int s = 0; s < 12; s++) { float e = expf(accS[s] - mx); pr[s] = e; sum += e; }
        float rinv = 1.0f / sum;
        #pragma unroll
        for (int s = 0; s < 12; s++) pr[s] *= rinv;
    }

    // ---- PV: lane lam = t owns output row; chunk over 8 cols ----
    for (int ch = 0; ch < 16; ch++) {
        float of[8];
        #pragma unroll
        for (int i = 0; i < 8; i++) of[i] = 0.f;
        if (lam < 12) {
            #pragma unroll
            for (int s = 0; s < 12; s++) {
                bf16x8v vv = *(const bf16x8v*)&vL[g][s][ch * 8];
                float vf[8]; unpack8(vv, vf);
                #pragma unroll
                for (int i = 0; i < 8; i++) of[i] += pr[s] * vf[i];
            }
        }
        if constexpr (SUM == 0) {
            if (lam < 12) {
                int row = baseRow + g * 12 + lam;
                if (row < totalRows) {
                    uint32_t w[4];
                    #pragma unroll
                    for (int d = 0; d < 4; d++)
                        w[d] = (uint32_t)f2bf(of[2 * d]) | ((uint32_t)f2bf(of[2 * d + 1]) << 16);
                    uint4 pk = make_uint4(w[0], w[1], w[2], w[3]);
                    *(uint4*)(io + (size_t)row * 128 + ch * 8) = pk;
                }
            }
        } else {
            #pragma unroll
            for (int i = 0; i < 8; i++) {
                float v = of[i];
                v += __shfl_xor(v, 1);
                v += __shfl_xor(v, 2);
                v += __shfl_xor(v, 4);
                v += __shfl_xor(v, 8);
                of[i] = v;
            }
            if (lam == 0 && (baseRow + g * 12) < totalRows) {
                int node = blockIdx.x * 4 + g;
                float4 f0 = make_float4(of[0], of[1], of[2], of[3]);
                float4 f1 = make_float4(of[4], of[5], of[6], of[7]);
                *(float4*)(outF + (size_t)node * 128 + ch * 8) = f0;
                *(float4*)(outF + (size_t)node * 128 + ch * 8 + 4) = f1;
            }
        }
    }
}

// ---------------- conv2 restricted to selected nodes (bf16 in, bf16 out) ----------------

__global__ __launch_bounds__(256) void conv2_kernel(
    const bf16* __restrict__ emb1, const int* __restrict__ node_idx, const int* __restrict__ rs,
    const int* __restrict__ csr, const int* __restrict__ deg, const float* __restrict__ Wlt,
    const float* __restrict__ Wrt, const float* __restrict__ b2, bf16* __restrict__ emb2) {
    int bb = blockIdx.x, tid = threadIdx.x;
    int n = node_idx[bb];
    __shared__ float mean_s[12][129], hsel_s[12][129];
    for (int idx = tid; idx < 1536; idx += 256) hsel_s[idx >> 7][idx & 127] = ldv(&emb1[(size_t)n * 1536 + idx]);
    float acc[6] = {0.f, 0.f, 0.f, 0.f, 0.f, 0.f};
    int beg = rs[n], end = rs[n + 1];
    for (int e = beg; e < end; e++) {
        int nbr = csr[e];
        const bf16* r = emb1 + (size_t)nbr * 1536;
        #pragma unroll
        for (int k = 0; k < 6; k++) acc[k] += ldv(&r[k * 256 + tid]);
    }
    float inv = 1.0f / fmaxf((float)deg[n], 1.0f);
    #pragma unroll
    for (int k = 0; k < 6; k++) {
        int idx = k * 256 + tid;
        mean_s[idx >> 7][idx & 127] = acc[k] * inv;
    }
    __syncthreads();
    int i = tid & 127, th = tid >> 7;
    #pragma unroll
    for (int r2 = 0; r2 < 6; r2++) {
        int t = r2 * 2 + th;
        float o = b2[i];
        for (int j = 0; j < 128; j++) o += mean_s[t][j] * Wlt[j * 128 + i] + hsel_s[t][j] * Wrt[j * 128 + i];
        stv(&emb2[(size_t)bb * 1536 + t * 128 + i], fmaxf(o, 0.0f));
    }
}

// ---------------- MLP head ----------------

__global__ __launch_bounds__(256) void head_kernel(
    const float* __restrict__ embF, const float* __restrict__ apart, const float* __restrict__ fc1Wt,
    const float* __restrict__ fc1b, const float* __restrict__ fc2Wt, const float* __restrict__ fc2b,
    const float* __restrict__ fc3W, const float* __restrict__ fc3b, float* __restrict__ out) {
    int bb = blockIdx.x, tid = threadIdx.x;
    __shared__ float in_s[138], a1[256], a2[128], red[128];
    if (tid < 128) in_s[tid] = embF[(size_t)bb * 128 + tid];
    else if (tid < 138) in_s[tid] = apart[(size_t)bb * 10 + tid - 128];
    __syncthreads();
    float o = fc1b[tid];
    for (int j = 0; j < 138; j++) o += in_s[j] * fc1Wt[j * 256 + tid];
    a1[tid] = o >= 0.f ? o : 0.1f * o;
    __syncthreads();
    if (tid < 128) {
        float o2 = fc2b[tid];
        for (int j = 0; j < 256; j++) o2 += a1[j] * fc2Wt[j * 128 + tid];
        a2[tid] = o2 >= 0.f ? o2 : 0.05f * o2;
    }
    __syncthreads();
    if (tid < 128) red[tid] = a2[tid] * fc3W[tid];
    __syncthreads();
    for (int s = 64; s > 0; s >>= 1) {
        if (tid < s) red[tid] += red[tid + s];
        __syncthreads();
    }
    if (tid == 0) out[bb] = red[0] + fc3b[0];
}

// ---------------- launch ----------------

extern "C" void kernel_launch(void* const* d_in, const int* in_sizes, int n_in,
                              void* d_out, int out_size, void* d_ws, size_t ws_size,
                              hipStream_t stream) {
    const float* x    = (const float*)d_in[0];
    const int* ei     = (const int*)d_in[1];
    const int* nidx   = (const int*)d_in[2];
    const float* apart= (const float*)d_in[3];
    const float* c1Wl = (const float*)d_in[4];
    const float* c1Wr = (const float*)d_in[5];
    const float* c1b  = (const float*)d_in[6];
    const float* c2Wl = (const float*)d_in[7];
    const float* c2Wr = (const float*)d_in[8];
    const float* c2b  = (const float*)d_in[9];
    const float* Wq   = (const float*)d_in[10];
    const float* bq   = (const float*)d_in[11];
    const float* Wk   = (const float*)d_in[12];
    const float* bk   = (const float*)d_in[13];
    const float* Wv   = (const float*)d_in[14];
    const float* bv   = (const float*)d_in[15];
    const float* fc1W = (const float*)d_in[16];
    const float* fc1b = (const float*)d_in[17];
    const float* fc2W = (const float*)d_in[18];
    const float* fc2b = (const float*)d_in[19];
    const float* fc3W = (const float*)d_in[20];
    const float* fc3b = (const float*)d_in[21];

    int N = in_sizes[0] / 144;
    int E = in_sizes[1] / 2;
    int B = in_sizes[2];
    float* out = (float*)d_out;
    char* ws = (char*)d_ws;

    size_t off = 0;
    auto A = [&](size_t bytes) -> void* {
        void* q = ws + off;
        off = (off + bytes + 255) & ~(size_t)255;
        return q;
    };
    bf16* emb1 = (bf16*)A((size_t)N * 1536 * 2);
    size_t xtBytes = (size_t)N * 144 * 4;
    float* xT = (float*)A(xtBytes);
    // alias emb2 (bf16) + embF (f32) onto xT (dead after conv1)
    size_t e2Bytes = (((size_t)B * 1536 * 2) + 255) & ~(size_t)255;
    bf16* emb2; float* embF;
    bool aliased = (e2Bytes + (size_t)B * 128 * 4 <= xtBytes);
    if (aliased) {
        emb2 = (bf16*)xT;
        embF = (float*)((char*)xT + e2Bytes);
    } else {
        emb2 = (bf16*)A((size_t)B * 1536 * 2);
        embF = (float*)A((size_t)B * 128 * 4);
    }
    unsigned short* Bpack = (unsigned short*)A(3 * 16384 * 2);
    float* Wl2t  = (float*)A(16384 * 4);
    float* Wr2t  = (float*)A(16384 * 4);
    float* fc1Wt = (float*)A(138 * 256 * 4);
    float* fc2Wt = (float*)A(256 * 128 * 4);
    int* deg = (int*)A((size_t)N * 4);
    int* rsb = (int*)A((size_t)(N + 1) * 4);
    int* cur = (int*)A((size_t)N * 4);
    int* csr = (int*)A((size_t)E * 4);
    if (off > ws_size) {
        sentinel_kernel<<<(out_size + 255) / 256, 256, 0, stream>>>(out, out_size);
        return;
    }

    (void)hipMemsetAsync(deg, 0, (size_t)N * 4, stream);
    (void)hipMemsetAsync(cur, 0, (size_t)N * 4, stream);

    int eb = (E + 255) / 256;
    transpose_x_kernel<<<(12 * N + 255) / 256, 256, 0, stream>>>(x, xT, N);
    deg_kernel<<<eb, 256, 0, stream>>>(ei, deg, E);
    scan_kernel<<<1, 1024, 0, stream>>>(deg, rsb, N);
    fill_kernel<<<eb, 256, 0, stream>>>(ei, rsb, cur, csr, E);

    pack_qkv_kernel<<<192, 256, 0, stream>>>(Wq, Wk, Wv, Bpack);
    transpose_kernel<<<64, 256, 0, stream>>>(c2Wl, Wl2t, 128, 128);
    transpose_kernel<<<64, 256, 0, stream>>>(c2Wr, Wr2t, 128, 128);
    transpose_kernel<<<(256 * 138 + 255) / 256, 256, 0, stream>>>(fc1W, fc1Wt, 256, 138);
    transpose_kernel<<<128, 256, 0, stream>>>(fc2W, fc2Wt, 128, 256);

    conv1_kernel<<<N, 128, 0, stream>>>(xT, rsb, csr, deg, c1Wl, c1Wr, c1b, emb1);

    int rows1 = N * 12;
    mfma_attn_kernel<0><<<(rows1 + 47) / 48, 64, 0, stream>>>(
        (unsigned short*)emb1, Bpack, bq, bk, bv, nullptr, rows1);

    conv2_kernel<<<B, 256, 0, stream>>>(emb1, nidx, rsb, csr, deg, Wl2t, Wr2t, c2b, emb2);

    int rows2 = B * 12;
    mfma_attn_kernel<1><<<(rows2 + 47) / 48, 64, 0, stream>>>(
        (unsigned short*)emb2, Bpack, bq, bk, bv, embF, rows2);

    head_kernel<<<B, 256, 0, stream>>>(embF, apart, fc1Wt, fc1b, fc2Wt, fc2b, fc3W, fc3b, out);
}

// Round 5
// 1110.515 us; speedup vs baseline: 3.9211x; 1.1123x over previous
//
#include <hip/hip_runtime.h>
#include <hip/hip_bf16.h>
#include <cstddef>
#include <cstdint>
#include <cmath>

typedef __attribute__((ext_vector_type(8))) short bf16x8v;  // MFMA A/B frag (8 bf16)
typedef __attribute__((ext_vector_type(4))) float f32x4;    // MFMA C/D frag

__device__ inline unsigned short f2bf(float x) {  // RNE
    uint32_t u = __float_as_uint(x);
    uint32_t r = (u + 0x7fffu + ((u >> 16) & 1u)) >> 16;
    return (unsigned short)r;
}

__device__ inline void unpack8(bf16x8v v, float* f) {
    union { bf16x8v v8; uint32_t u[4]; } cv; cv.v8 = v;
    #pragma unroll
    for (int d = 0; d < 4; d++) {
        uint32_t w = cv.u[d];
        f[2 * d]     = __uint_as_float(w << 16);
        f[2 * d + 1] = __uint_as_float(w & 0xffff0000u);
    }
}

// ---------------- graph preprocessing ----------------

// x [12][N][12] f32 -> xTb [N][144] bf16, coalesced via LDS staging (64 nodes/block)
__global__ __launch_bounds__(256) void transpose_xb_kernel(const float* __restrict__ x,
                                                           unsigned short* __restrict__ xTb, int N) {
    __shared__ __align__(16) unsigned short sm[64][144];
    int n0 = blockIdx.x * 64;
    int nodes = min(64, N - n0);
    int tid = threadIdx.x;
    for (int t = 0; t < 12; t++) {
        const float* src = x + ((size_t)t * N + n0) * 12;
        for (int k = tid; k < nodes * 12; k += 256)
            sm[k / 12][t * 12 + k % 12] = f2bf(src[k]);
    }
    __syncthreads();
    int chunks = nodes * 18;  // 16B chunks
    const uint4* smv = (const uint4*)&sm[0][0];
    uint4* dst = (uint4*)(xTb + (size_t)n0 * 144);
    for (int c = tid; c < chunks; c += 256) dst[c] = smv[c];
}

__global__ void deg_kernel(const int* __restrict__ ei, int* __restrict__ deg, int E) {
    int e = blockIdx.x * 256 + threadIdx.x;
    if (e < E) atomicAdd(&deg[ei[E + e]], 1);
}

__global__ void scan_kernel(const int* __restrict__ deg, int* __restrict__ rs, int N) {
    __shared__ int part[1024];
    int tid = threadIdx.x;
    int chunk = (N + 1023) >> 10;
    int base = tid * chunk;
    int s = 0;
    for (int k = 0; k < chunk; k++) { int i = base + k; if (i < N) s += deg[i]; }
    part[tid] = s;
    __syncthreads();
    for (int off = 1; off < 1024; off <<= 1) {
        int v = (tid >= off) ? part[tid - off] : 0;
        __syncthreads();
        part[tid] += v;
        __syncthreads();
    }
    int run = part[tid] - s;
    for (int k = 0; k < chunk; k++) {
        int i = base + k;
        if (i < N) { rs[i] = run; run += deg[i]; }
    }
    if (tid == 1023) rs[N] = part[1023];
}

__global__ void fill_kernel(const int* __restrict__ ei, const int* __restrict__ rs,
                            int* __restrict__ cur, int* __restrict__ csr, int E) {
    int e = blockIdx.x * 256 + threadIdx.x;
    if (e < E) {
        int d = ei[E + e];
        int pos = atomicAdd(&cur[d], 1);
        csr[rs[d] + pos] = ei[e];
    }
}

// merged weight prep: Wl2t, Wr2t, fc1Wt, fc2Wt transposes + qkv MFMA-B packing
__global__ void prep_weights_kernel(
    const float* __restrict__ c2Wl, const float* __restrict__ c2Wr,
    const float* __restrict__ fc1W, const float* __restrict__ fc2W,
    const float* __restrict__ Wq, const float* __restrict__ Wk, const float* __restrict__ Wv,
    float* __restrict__ Wl2t, float* __restrict__ Wr2t,
    float* __restrict__ fc1Wt, float* __restrict__ fc2Wt, unsigned short* __restrict__ Bpack) {
    int idx = blockIdx.x * 256 + threadIdx.x;
    if (idx < 16384) {
        Wl2t[(idx % 128) * 128 + idx / 128] = c2Wl[idx];
        return;
    }
    idx -= 16384;
    if (idx < 16384) {
        Wr2t[(idx % 128) * 128 + idx / 128] = c2Wr[idx];
        return;
    }
    idx -= 16384;
    if (idx < 35328) {  // fc1W [256][138]
        fc1Wt[(idx % 138) * 256 + idx / 138] = fc1W[idx];
        return;
    }
    idx -= 35328;
    if (idx < 32768) {  // fc2W [128][256]
        fc2Wt[(idx % 256) * 128 + idx / 256] = fc2W[idx];
        return;
    }
    idx -= 32768;
    if (idx < 3 * 16384) {
        int p = idx >> 14, rem = idx & 16383;
        int kc = rem >> 12, rem2 = rem & 4095;
        int nt = rem2 >> 9, li = rem2 & 511;
        int l = li >> 3, i = li & 7;
        int col = nt * 16 + (l & 15);
        int j = kc * 32 + (l >> 4) * 8 + i;
        const float* W = (p == 0) ? Wq : (p == 1) ? Wk : Wv;
        Bpack[idx] = f2bf(W[col * 128 + j]);
    }
}

__global__ void sentinel_kernel(float* out, int n) {
    int i = blockIdx.x * 256 + threadIdx.x;
    if (i < n) out[i] = 12345.0f;
}

// ---------------- conv1: vectorized 14-edge-parallel gather + fused GEMM + relu ----------------

__global__ __launch_bounds__(256) void conv1_kernel(
    const unsigned short* __restrict__ xTb, const int* __restrict__ rs, const int* __restrict__ csr,
    const float* __restrict__ Wl, const float* __restrict__ Wr,
    const float* __restrict__ b, unsigned short* __restrict__ emb1) {
    int n = blockIdx.x, tid = threadIdx.x;
    __shared__ float s_part[14][144];
    __shared__ float s_mean[144], s_xx[144];
    __shared__ float s_wl[128 * 13], s_wr[128 * 13], s_b[128];
    for (int i = tid; i < 1536; i += 256) {
        int h = i / 12, j = i % 12;
        s_wl[h * 13 + j] = Wl[i];
        s_wr[h * 13 + j] = Wr[i];
    }
    if (tid < 128) s_b[tid] = b[tid];
    int beg = rs[n], end = rs[n + 1];
    int group = tid / 18, d8 = tid % 18;
    if (group < 14) {
        float acc[8] = {0.f, 0.f, 0.f, 0.f, 0.f, 0.f, 0.f, 0.f};
        for (int e = beg + group; e < end; e += 14) {
            int nbr = csr[e];
            bf16x8v v = *(const bf16x8v*)(xTb + (size_t)nbr * 144 + d8 * 8);
            float f[8]; unpack8(v, f);
            #pragma unroll
            for (int i = 0; i < 8; i++) acc[i] += f[i];
        }
        #pragma unroll
        for (int i = 0; i < 8; i++) s_part[group][d8 * 8 + i] = acc[i];
    }
    if (tid >= 224 && tid < 242) {  // self row (these threads also did gather above)
        int dd = tid - 224;
        bf16x8v v = *(const bf16x8v*)(xTb + (size_t)n * 144 + dd * 8);
        float f[8]; unpack8(v, f);
        #pragma unroll
        for (int i = 0; i < 8; i++) s_xx[dd * 8 + i] = f[i];
    }
    __syncthreads();
    if (tid < 144) {
        float s = 0.f;
        #pragma unroll
        for (int g = 0; g < 14; g++) s += s_part[g][tid];
        s_mean[tid] = s / fmaxf((float)(end - beg), 1.0f);
    }
    __syncthreads();
    int i = tid & 127, th = tid >> 7;
    #pragma unroll
    for (int r = 0; r < 6; r++) {
        int t = r * 2 + th;
        float o = s_b[i];
        #pragma unroll
        for (int j = 0; j < 12; j++)
            o += s_mean[t * 12 + j] * s_wl[i * 13 + j] + s_xx[t * 12 + j] * s_wr[i * 13 + j];
        emb1[(size_t)n * 1536 + t * 128 + i] = f2bf(fmaxf(o, 0.0f));
    }
}

// ---------------- fused MFMA attention: 1 wave = 4 nodes (48 rows) ----------------

template <int SUM>
__global__ __launch_bounds__(64) void mfma_attn_kernel(
    unsigned short* io, const unsigned short* __restrict__ Bpack,
    const float* __restrict__ bq, const float* __restrict__ bk, const float* __restrict__ bv,
    float* __restrict__ outF, int totalRows) {
    int l = threadIdx.x;
    int g = l >> 4, lam = l & 15;
    int baseRow = blockIdx.x * 48;

    __shared__ unsigned short qL[4][12][136];
    __shared__ unsigned short kL[4][12][136];
    __shared__ unsigned short vL[4][12][136];

    bf16x8v afrag[3][4];
    #pragma unroll
    for (int rt = 0; rt < 3; rt++) {
        int row = baseRow + rt * 16 + lam;
        if (row > totalRows - 1) row = totalRows - 1;
        #pragma unroll
        for (int kc = 0; kc < 4; kc++)
            afrag[rt][kc] = *(const bf16x8v*)(io + (size_t)row * 128 + kc * 32 + g * 8);
    }

    const float qscale = 0.08838834764831845f;  // 1/sqrt(128)

    #pragma unroll
    for (int p = 0; p < 3; p++) {
        f32x4 acc[3][8];
        #pragma unroll
        for (int rt = 0; rt < 3; rt++)
            #pragma unroll
            for (int nt = 0; nt < 8; nt++) acc[rt][nt] = (f32x4){0.f, 0.f, 0.f, 0.f};
        const unsigned short* Bp = Bpack + p * 16384;
        #pragma unroll
        for (int kc = 0; kc < 4; kc++) {
            #pragma unroll
            for (int nt = 0; nt < 8; nt++) {
                bf16x8v bfrag = *(const bf16x8v*)(Bp + (kc * 8 + nt) * 512 + l * 8);
                #pragma unroll
                for (int rt = 0; rt < 3; rt++)
                    acc[rt][nt] = __builtin_amdgcn_mfma_f32_16x16x32_bf16(afrag[rt][kc], bfrag, acc[rt][nt], 0, 0, 0);
            }
        }
        const float* bias = (p == 0) ? bq : (p == 1) ? bk : bv;
        #pragma unroll
        for (int nt = 0; nt < 8; nt++) {
            float bval = bias[nt * 16 + lam];
            #pragma unroll
            for (int rt = 0; rt < 3; rt++) {
                int rstart = 16 * rt + 4 * g;
                int m = rstart / 12;
                int tbase = rstart - 12 * m;
                #pragma unroll
                for (int r = 0; r < 4; r++) {
                    float val = acc[rt][nt][r] + bval;
                    if (p == 0) val *= qscale;
                    unsigned short hv = f2bf(val);
                    int t = tbase + r, c = nt * 16 + lam;
                    if (p == 0) qL[m][t][c] = hv;
                    else if (p == 1) kL[m][t][c] = hv;
                    else vL[m][t][c] = hv;
                }
            }
        }
    }
    __syncthreads();

    float pr[12];
    if (lam < 12) {
        float accS[12];
        #pragma unroll
        for (int s = 0; s < 12; s++) accS[s] = 0.f;
        for (int ch = 0; ch < 16; ch++) {
            bf16x8v qv = *(const bf16x8v*)&qL[g][lam][ch * 8];
            float qf[8]; unpack8(qv, qf);
            #pragma unroll
            for (int s = 0; s < 12; s++) {
                bf16x8v kv = *(const bf16x8v*)&kL[g][s][ch * 8];
                float kf[8]; unpack8(kv, kf);
                #pragma unroll
                for (int i = 0; i < 8; i++) accS[s] += qf[i] * kf[i];
            }
        }
        float mx = -1e30f;
        #pragma unroll
        for (int s = 0; s < 12; s++) mx = fmaxf(mx, accS[s]);
        float sum = 0.f;
        #pragma unroll
        for (int s = 0; s < 12; s++) { float e = expf(accS[s] - mx); pr[s] = e; sum += e; }
        float rinv = 1.0f / sum;
        #pragma unroll
        for (int s = 0; s < 12; s++) pr[s] *= rinv;
    }

    for (int ch = 0; ch < 16; ch++) {
        float of[8];
        #pragma unroll
        for (int i = 0; i < 8; i++) of[i] = 0.f;
        if (lam < 12) {
            #pragma unroll
            for (int s = 0; s < 12; s++) {
                bf16x8v vv = *(const bf16x8v*)&vL[g][s][ch * 8];
                float vf[8]; unpack8(vv, vf);
                #pragma unroll
                for (int i = 0; i < 8; i++) of[i] += pr[s] * vf[i];
            }
        }
        if constexpr (SUM == 0) {
            if (lam < 12) {
                int row = baseRow + g * 12 + lam;
                if (row < totalRows) {
                    uint32_t w[4];
                    #pragma unroll
                    for (int d = 0; d < 4; d++)
                        w[d] = (uint32_t)f2bf(of[2 * d]) | ((uint32_t)f2bf(of[2 * d + 1]) << 16);
                    *(uint4*)(io + (size_t)row * 128 + ch * 8) = make_uint4(w[0], w[1], w[2], w[3]);
                }
            }
        } else {
            #pragma unroll
            for (int i = 0; i < 8; i++) {
                float v = of[i];
                v += __shfl_xor(v, 1);
                v += __shfl_xor(v, 2);
                v += __shfl_xor(v, 4);
                v += __shfl_xor(v, 8);
                of[i] = v;
            }
            if (lam == 0 && (baseRow + g * 12) < totalRows) {
                int node = blockIdx.x * 4 + g;
                *(float4*)(outF + (size_t)node * 128 + ch * 8) = make_float4(of[0], of[1], of[2], of[3]);
                *(float4*)(outF + (size_t)node * 128 + ch * 8 + 4) = make_float4(of[4], of[5], of[6], of[7]);
            }
        }
    }
}

// ---------------- conv2: vectorized full-row gather on selected nodes ----------------

__global__ __launch_bounds__(256) void conv2_kernel(
    const unsigned short* __restrict__ emb1, const int* __restrict__ node_idx,
    const int* __restrict__ rs, const int* __restrict__ csr,
    const float* __restrict__ Wlt, const float* __restrict__ Wrt,
    const float* __restrict__ b2, unsigned short* __restrict__ emb2) {
    int bb = blockIdx.x, tid = threadIdx.x;
    int n = node_idx[bb];
    __shared__ float s_mean[1536], s_h[1536];
    int beg = rs[n], end = rs[n + 1];
    if (tid < 192) {  // waves 0-2: edge gather, 16B/lane covers full 3072B row
        float acc[8] = {0.f, 0.f, 0.f, 0.f, 0.f, 0.f, 0.f, 0.f};
        for (int e = beg; e < end; e++) {
            int nbr = csr[e];
            bf16x8v v = *(const bf16x8v*)(emb1 + (size_t)nbr * 1536 + tid * 8);
            float f[8]; unpack8(v, f);
            #pragma unroll
            for (int i = 0; i < 8; i++) acc[i] += f[i];
        }
        float inv = 1.0f / fmaxf((float)(end - beg), 1.0f);
        #pragma unroll
        for (int i = 0; i < 8; i++) s_mean[tid * 8 + i] = acc[i] * inv;
    } else {          // wave 3: self row
        for (int c = tid - 192; c < 192; c += 64) {
            bf16x8v v = *(const bf16x8v*)(emb1 + (size_t)n * 1536 + c * 8);
            float f[8]; unpack8(v, f);
            #pragma unroll
            for (int i = 0; i < 8; i++) s_h[c * 8 + i] = f[i];
        }
    }
    __syncthreads();
    int i = tid & 127, th = tid >> 7;
    #pragma unroll
    for (int r = 0; r < 6; r++) {
        int t = r * 2 + th;
        float o = b2[i];
        for (int j = 0; j < 128; j++)
            o += s_mean[t * 128 + j] * Wlt[j * 128 + i] + s_h[t * 128 + j] * Wrt[j * 128 + i];
        emb2[(size_t)bb * 1536 + t * 128 + i] = f2bf(fmaxf(o, 0.0f));
    }
}

// ---------------- MLP head ----------------

__global__ __launch_bounds__(256) void head_kernel(
    const float* __restrict__ embF, const float* __restrict__ apart, const float* __restrict__ fc1Wt,
    const float* __restrict__ fc1b, const float* __restrict__ fc2Wt, const float* __restrict__ fc2b,
    const float* __restrict__ fc3W, const float* __restrict__ fc3b, float* __restrict__ out) {
    int bb = blockIdx.x, tid = threadIdx.x;
    __shared__ float in_s[138], a1[256], a2[128], red[128];
    if (tid < 128) in_s[tid] = embF[(size_t)bb * 128 + tid];
    else if (tid < 138) in_s[tid] = apart[(size_t)bb * 10 + tid - 128];
    __syncthreads();
    float o = fc1b[tid];
    for (int j = 0; j < 138; j++) o += in_s[j] * fc1Wt[j * 256 + tid];
    a1[tid] = o >= 0.f ? o : 0.1f * o;
    __syncthreads();
    if (tid < 128) {
        float o2 = fc2b[tid];
        for (int j = 0; j < 256; j++) o2 += a1[j] * fc2Wt[j * 128 + tid];
        a2[tid] = o2 >= 0.f ? o2 : 0.05f * o2;
    }
    __syncthreads();
    if (tid < 128) red[tid] = a2[tid] * fc3W[tid];
    __syncthreads();
    for (int s = 64; s > 0; s >>= 1) {
        if (tid < s) red[tid] += red[tid + s];
        __syncthreads();
    }
    if (tid == 0) out[bb] = red[0] + fc3b[0];
}

// ---------------- launch ----------------

extern "C" void kernel_launch(void* const* d_in, const int* in_sizes, int n_in,
                              void* d_out, int out_size, void* d_ws, size_t ws_size,
                              hipStream_t stream) {
    const float* x    = (const float*)d_in[0];
    const int* ei     = (const int*)d_in[1];
    const int* nidx   = (const int*)d_in[2];
    const float* apart= (const float*)d_in[3];
    const float* c1Wl = (const float*)d_in[4];
    const float* c1Wr = (const float*)d_in[5];
    const float* c1b  = (const float*)d_in[6];
    const float* c2Wl = (const float*)d_in[7];
    const float* c2Wr = (const float*)d_in[8];
    const float* c2b  = (const float*)d_in[9];
    const float* Wq   = (const float*)d_in[10];
    const float* bq   = (const float*)d_in[11];
    const float* Wk   = (const float*)d_in[12];
    const float* bk   = (const float*)d_in[13];
    const float* Wv   = (const float*)d_in[14];
    const float* bv   = (const float*)d_in[15];
    const float* fc1W = (const float*)d_in[16];
    const float* fc1b = (const float*)d_in[17];
    const float* fc2W = (const float*)d_in[18];
    const float* fc2b = (const float*)d_in[19];
    const float* fc3W = (const float*)d_in[20];
    const float* fc3b = (const float*)d_in[21];

    int N = in_sizes[0] / 144;
    int E = in_sizes[1] / 2;
    int B = in_sizes[2];
    float* out = (float*)d_out;
    char* ws = (char*)d_ws;

    size_t off = 0;
    auto A = [&](size_t bytes) -> void* {
        void* q = ws + off;
        off = (off + bytes + 255) & ~(size_t)255;
        return q;
    };
    unsigned short* emb1 = (unsigned short*)A((size_t)N * 1536 * 2);
    size_t xtBytes = (size_t)N * 144 * 2;
    unsigned short* xTb = (unsigned short*)A(xtBytes);
    // alias emb2 (bf16, B*1536*2 = 12.6MB) onto xTb (14.4MB, dead after conv1)
    unsigned short* emb2;
    if ((size_t)B * 1536 * 2 <= xtBytes) emb2 = xTb;
    else emb2 = (unsigned short*)A((size_t)B * 1536 * 2);
    float* embF  = (float*)A((size_t)B * 128 * 4);
    unsigned short* Bpack = (unsigned short*)A(3 * 16384 * 2);
    float* Wl2t  = (float*)A(16384 * 4);
    float* Wr2t  = (float*)A(16384 * 4);
    float* fc1Wt = (float*)A(138 * 256 * 4);
    float* fc2Wt = (float*)A(256 * 128 * 4);
    int* deg = (int*)A((size_t)N * 4);
    int* rsb = (int*)A((size_t)(N + 1) * 4);
    int* cur = (int*)A((size_t)N * 4);
    int* csr = (int*)A((size_t)E * 4);
    if (off > ws_size) {
        sentinel_kernel<<<(out_size + 255) / 256, 256, 0, stream>>>(out, out_size);
        return;
    }

    (void)hipMemsetAsync(deg, 0, (size_t)N * 4, stream);
    (void)hipMemsetAsync(cur, 0, (size_t)N * 4, stream);

    int eb = (E + 255) / 256;
    transpose_xb_kernel<<<(N + 63) / 64, 256, 0, stream>>>(x, xTb, N);
    deg_kernel<<<eb, 256, 0, stream>>>(ei, deg, E);
    scan_kernel<<<1, 1024, 0, stream>>>(deg, rsb, N);
    fill_kernel<<<eb, 256, 0, stream>>>(ei, rsb, cur, csr, E);

    prep_weights_kernel<<<(150016 + 255) / 256, 256, 0, stream>>>(
        c2Wl, c2Wr, fc1W, fc2W, Wq, Wk, Wv, Wl2t, Wr2t, fc1Wt, fc2Wt, Bpack);

    conv1_kernel<<<N, 256, 0, stream>>>(xTb, rsb, csr, c1Wl, c1Wr, c1b, emb1);

    int rows1 = N * 12;
    mfma_attn_kernel<0><<<(rows1 + 47) / 48, 64, 0, stream>>>(emb1, Bpack, bq, bk, bv, nullptr, rows1);

    conv2_kernel<<<B, 256, 0, stream>>>(emb1, nidx, rsb, csr, Wl2t, Wr2t, c2b, emb2);

    int rows2 = B * 12;
    mfma_attn_kernel<1><<<(rows2 + 47) / 48, 64, 0, stream>>>(emb2, Bpack, bq, bk, bv, embF, rows2);

    head_kernel<<<B, 256, 0, stream>>>(embF, apart, fc1Wt, fc1b, fc2Wt, fc2b, fc3W, fc3b, out);
}

// Round 6
// 1032.661 us; speedup vs baseline: 4.2167x; 1.0754x over previous
//
#include <hip/hip_runtime.h>
#include <hip/hip_bf16.h>
#include <cstddef>
#include <cstdint>
#include <cmath>

typedef __attribute__((ext_vector_type(8))) short bf16x8v;  // MFMA A/B frag (8 bf16)
typedef __attribute__((ext_vector_type(4))) float f32x4;    // MFMA C/D frag

__device__ inline unsigned short f2bf(float x) {  // RNE
    uint32_t u = __float_as_uint(x);
    uint32_t r = (u + 0x7fffu + ((u >> 16) & 1u)) >> 16;
    return (unsigned short)r;
}

__device__ inline void unpack8(bf16x8v v, float* f) {
    union { bf16x8v v8; uint32_t u[4]; } cv; cv.v8 = v;
    #pragma unroll
    for (int d = 0; d < 4; d++) {
        uint32_t w = cv.u[d];
        f[2 * d]     = __uint_as_float(w << 16);
        f[2 * d + 1] = __uint_as_float(w & 0xffff0000u);
    }
}

// ---------------- graph preprocessing ----------------

// x [12][N][12] f32 -> xTb [N][144] bf16, coalesced via LDS staging (64 nodes/block)
__global__ __launch_bounds__(256) void transpose_xb_kernel(const float* __restrict__ x,
                                                           unsigned short* __restrict__ xTb, int N) {
    __shared__ __align__(16) unsigned short sm[64][144];
    int n0 = blockIdx.x * 64;
    int nodes = min(64, N - n0);
    int tid = threadIdx.x;
    for (int t = 0; t < 12; t++) {
        const float* src = x + ((size_t)t * N + n0) * 12;
        for (int k = tid; k < nodes * 12; k += 256)
            sm[k / 12][t * 12 + k % 12] = f2bf(src[k]);
    }
    __syncthreads();
    int chunks = nodes * 18;  // 16B chunks
    const uint4* smv = (const uint4*)&sm[0][0];
    uint4* dst = (uint4*)(xTb + (size_t)n0 * 144);
    for (int c = tid; c < chunks; c += 256) dst[c] = smv[c];
}

__global__ void deg_kernel(const int* __restrict__ ei, int* __restrict__ deg, int E) {
    int e = blockIdx.x * 256 + threadIdx.x;
    if (e < E) atomicAdd(&deg[ei[E + e]], 1);
}

__global__ void scan_kernel(const int* __restrict__ deg, int* __restrict__ rs, int N) {
    __shared__ int part[1024];
    int tid = threadIdx.x;
    int chunk = (N + 1023) >> 10;
    int base = tid * chunk;
    int s = 0;
    for (int k = 0; k < chunk; k++) { int i = base + k; if (i < N) s += deg[i]; }
    part[tid] = s;
    __syncthreads();
    for (int off = 1; off < 1024; off <<= 1) {
        int v = (tid >= off) ? part[tid - off] : 0;
        __syncthreads();
        part[tid] += v;
        __syncthreads();
    }
    int run = part[tid] - s;
    for (int k = 0; k < chunk; k++) {
        int i = base + k;
        if (i < N) { rs[i] = run; run += deg[i]; }
    }
    if (tid == 1023) rs[N] = part[1023];
}

__global__ void fill_kernel(const int* __restrict__ ei, const int* __restrict__ rs,
                            int* __restrict__ cur, int* __restrict__ csr, int E) {
    int e = blockIdx.x * 256 + threadIdx.x;
    if (e < E) {
        int d = ei[E + e];
        int pos = atomicAdd(&cur[d], 1);
        csr[rs[d] + pos] = ei[e];
    }
}

// merged weight prep: Wl2t, Wr2t, fc1Wt, fc2Wt transposes + qkv MFMA-B packing
__global__ void prep_weights_kernel(
    const float* __restrict__ c2Wl, const float* __restrict__ c2Wr,
    const float* __restrict__ fc1W, const float* __restrict__ fc2W,
    const float* __restrict__ Wq, const float* __restrict__ Wk, const float* __restrict__ Wv,
    float* __restrict__ Wl2t, float* __restrict__ Wr2t,
    float* __restrict__ fc1Wt, float* __restrict__ fc2Wt, unsigned short* __restrict__ Bpack) {
    int idx = blockIdx.x * 256 + threadIdx.x;
    if (idx < 16384) {
        Wl2t[(idx % 128) * 128 + idx / 128] = c2Wl[idx];
        return;
    }
    idx -= 16384;
    if (idx < 16384) {
        Wr2t[(idx % 128) * 128 + idx / 128] = c2Wr[idx];
        return;
    }
    idx -= 16384;
    if (idx < 35328) {  // fc1W [256][138]
        fc1Wt[(idx % 138) * 256 + idx / 138] = fc1W[idx];
        return;
    }
    idx -= 35328;
    if (idx < 32768) {  // fc2W [128][256]
        fc2Wt[(idx % 256) * 128 + idx / 256] = fc2W[idx];
        return;
    }
    idx -= 32768;
    if (idx < 3 * 16384) {
        int p = idx >> 14, rem = idx & 16383;
        int kc = rem >> 12, rem2 = rem & 4095;
        int nt = rem2 >> 9, li = rem2 & 511;
        int l = li >> 3, i = li & 7;
        int col = nt * 16 + (l & 15);
        int j = kc * 32 + (l >> 4) * 8 + i;
        const float* W = (p == 0) ? Wq : (p == 1) ? Wk : Wv;
        Bpack[idx] = f2bf(W[col * 128 + j]);
    }
}

__global__ void sentinel_kernel(float* out, int n) {
    int i = blockIdx.x * 256 + threadIdx.x;
    if (i < n) out[i] = 12345.0f;
}

// ---------------- conv1: vectorized 14-edge-parallel gather + fused GEMM + relu ----------------

__global__ __launch_bounds__(256) void conv1_kernel(
    const unsigned short* __restrict__ xTb, const int* __restrict__ rs, const int* __restrict__ csr,
    const float* __restrict__ Wl, const float* __restrict__ Wr,
    const float* __restrict__ b, unsigned short* __restrict__ emb1) {
    int n = blockIdx.x, tid = threadIdx.x;
    __shared__ float s_part[14][144];
    __shared__ float s_mean[144], s_xx[144];
    __shared__ float s_wl[128 * 13], s_wr[128 * 13], s_b[128];
    for (int i = tid; i < 1536; i += 256) {
        int h = i / 12, j = i % 12;
        s_wl[h * 13 + j] = Wl[i];
        s_wr[h * 13 + j] = Wr[i];
    }
    if (tid < 128) s_b[tid] = b[tid];
    int beg = rs[n], end = rs[n + 1];
    int group = tid / 18, d8 = tid % 18;
    if (group < 14) {
        float acc[8] = {0.f, 0.f, 0.f, 0.f, 0.f, 0.f, 0.f, 0.f};
        for (int e = beg + group; e < end; e += 14) {
            int nbr = csr[e];
            bf16x8v v = *(const bf16x8v*)(xTb + (size_t)nbr * 144 + d8 * 8);
            float f[8]; unpack8(v, f);
            #pragma unroll
            for (int i = 0; i < 8; i++) acc[i] += f[i];
        }
        #pragma unroll
        for (int i = 0; i < 8; i++) s_part[group][d8 * 8 + i] = acc[i];
    }
    if (tid >= 224 && tid < 242) {  // self row
        int dd = tid - 224;
        bf16x8v v = *(const bf16x8v*)(xTb + (size_t)n * 144 + dd * 8);
        float f[8]; unpack8(v, f);
        #pragma unroll
        for (int i = 0; i < 8; i++) s_xx[dd * 8 + i] = f[i];
    }
    __syncthreads();
    if (tid < 144) {
        float s = 0.f;
        #pragma unroll
        for (int g = 0; g < 14; g++) s += s_part[g][tid];
        s_mean[tid] = s / fmaxf((float)(end - beg), 1.0f);
    }
    __syncthreads();
    int i = tid & 127, th = tid >> 7;
    #pragma unroll
    for (int r = 0; r < 6; r++) {
        int t = r * 2 + th;
        float o = s_b[i];
        #pragma unroll
        for (int j = 0; j < 12; j++)
            o += s_mean[t * 12 + j] * s_wl[i * 13 + j] + s_xx[t * 12 + j] * s_wr[i * 13 + j];
        emb1[(size_t)n * 1536 + t * 128 + i] = f2bf(fmaxf(o, 0.0f));
    }
}

// ---------------- fully-MFMA attention: 1 wave = 4 nodes (48 rows) ----------------
// LDS (u16 elements): qL [48][136] @0, kL [48][136] @6528, vT [128][52] @13056 (V transposed)
// wL [4][16][24] aliases qL rows 0-11 (dead after QK phase). Total 39424 B.

template <int SUM>
__global__ __launch_bounds__(64) void mfma_attn_kernel(
    unsigned short* io, const unsigned short* __restrict__ Bpack,
    const float* __restrict__ bq, const float* __restrict__ bk, const float* __restrict__ bv,
    float* __restrict__ outF, int totalRows) {
    __shared__ __align__(16) unsigned short lds[19712];
    int l = threadIdx.x;
    int g = l >> 4, lam = l & 15;
    int baseRow = blockIdx.x * 48;

    // ---- phase 1: projections q,k,v via MFMA ----
    bf16x8v afrag[3][4];
    #pragma unroll
    for (int rt = 0; rt < 3; rt++) {
        int row = baseRow + rt * 16 + lam;
        if (row > totalRows - 1) row = totalRows - 1;
        #pragma unroll
        for (int kc = 0; kc < 4; kc++)
            afrag[rt][kc] = *(const bf16x8v*)(io + (size_t)row * 128 + kc * 32 + g * 8);
    }
    const float qscale = 0.08838834764831845f;  // 1/sqrt(128)

    #pragma unroll
    for (int p = 0; p < 3; p++) {
        f32x4 acc[3][8];
        #pragma unroll
        for (int rt = 0; rt < 3; rt++)
            #pragma unroll
            for (int nt = 0; nt < 8; nt++) acc[rt][nt] = (f32x4){0.f, 0.f, 0.f, 0.f};
        const unsigned short* Bp = Bpack + p * 16384;
        #pragma unroll
        for (int kc = 0; kc < 4; kc++) {
            #pragma unroll
            for (int nt = 0; nt < 8; nt++) {
                bf16x8v bfrag = *(const bf16x8v*)(Bp + (kc * 8 + nt) * 512 + l * 8);
                #pragma unroll
                for (int rt = 0; rt < 3; rt++)
                    acc[rt][nt] = __builtin_amdgcn_mfma_f32_16x16x32_bf16(afrag[rt][kc], bfrag, acc[rt][nt], 0, 0, 0);
            }
        }
        const float* bias = (p == 0) ? bq : (p == 1) ? bk : bv;
        #pragma unroll
        for (int nt = 0; nt < 8; nt++) {
            float bval = bias[nt * 16 + lam];
            #pragma unroll
            for (int rt = 0; rt < 3; rt++) {
                int row0 = 16 * rt + 4 * g;  // local row (time-major within 48-block)
                if (p < 2) {
                    int base = (p == 0) ? 0 : 6528;
                    #pragma unroll
                    for (int r = 0; r < 4; r++) {
                        float val = acc[rt][nt][r] + bval;
                        if (p == 0) val *= qscale;
                        lds[base + (row0 + r) * 136 + nt * 16 + lam] = f2bf(val);
                    }
                } else {  // v: transposed, packed b64 write (4 consecutive local rows)
                    uint32_t w0 = (uint32_t)f2bf(acc[rt][nt][0] + bval) | ((uint32_t)f2bf(acc[rt][nt][1] + bval) << 16);
                    uint32_t w1 = (uint32_t)f2bf(acc[rt][nt][2] + bval) | ((uint32_t)f2bf(acc[rt][nt][3] + bval) << 16);
                    *(uint2*)&lds[13056 + (nt * 16 + lam) * 52 + row0] = make_uint2(w0, w1);
                }
            }
        }
    }
    __syncthreads();

    // ---- phase 2: QK^T via MFMA + lane-parallel softmax, per node ----
    float wv[4][4];  // [node][reg]
    #pragma unroll
    for (int n = 0; n < 4; n++) {
        int qrow = 12 * n + lam;
        if (qrow > 47) qrow = 47;  // lam 12-15: duplicate row (masked below)
        f32x4 sc = (f32x4){0.f, 0.f, 0.f, 0.f};
        #pragma unroll
        for (int kc = 0; kc < 4; kc++) {
            bf16x8v qa = *(const bf16x8v*)&lds[qrow * 136 + kc * 32 + g * 8];
            bf16x8v kb = *(const bf16x8v*)&lds[6528 + qrow * 136 + kc * 32 + g * 8];
            sc = __builtin_amdgcn_mfma_f32_16x16x32_bf16(qa, kb, sc, 0, 0, 0);
        }
        #pragma unroll
        for (int r = 0; r < 4; r++) {
            float s = (lam < 12) ? sc[r] : -3.0e38f;  // mask cols s>=12
            float mx = s;
            mx = fmaxf(mx, __shfl_xor(mx, 1)); mx = fmaxf(mx, __shfl_xor(mx, 2));
            mx = fmaxf(mx, __shfl_xor(mx, 4)); mx = fmaxf(mx, __shfl_xor(mx, 8));
            float e = __expf(s - mx);
            float sm = e;
            sm += __shfl_xor(sm, 1); sm += __shfl_xor(sm, 2);
            sm += __shfl_xor(sm, 4); sm += __shfl_xor(sm, 8);
            wv[n][r] = e / sm;
        }
    }
    __syncthreads();  // all QK reads done before wL (aliased onto qL) writes
    #pragma unroll
    for (int n = 0; n < 4; n++)
        #pragma unroll
        for (int r = 0; r < 4; r++)
            lds[(n * 16 + 4 * g + r) * 24 + lam] = f2bf(wv[n][r]);  // wL[n][t][s]
    __syncthreads();

    // ---- phase 3: PV transposed: D[d][t] = sum_s V^T[d][s] * W[t][s] ----
    const bf16x8v zero8 = (bf16x8v){0, 0, 0, 0, 0, 0, 0, 0};
    #pragma unroll
    for (int n = 0; n < 4; n++) {
        bf16x8v wfrag = zero8;
        if (g < 2) wfrag = *(const bf16x8v*)&lds[(n * 16 + lam) * 24 + g * 8];
        int sA = 12 * n + g * 8;
        int sB = sA + 4;
        if (sB > 44) sB = 44;  // n=3,g=1: clamp (those W cols are zero)
        #pragma unroll
        for (int nt = 0; nt < 8; nt++) {
            bf16x8v vfrag = zero8;
            if (g < 2) {
                int dbase = 13056 + (nt * 16 + lam) * 52;
                uint2 lo = *(const uint2*)&lds[dbase + sA];
                uint2 hi = *(const uint2*)&lds[dbase + sB];
                union { uint32_t u[4]; bf16x8v v; } cv;
                cv.u[0] = lo.x; cv.u[1] = lo.y; cv.u[2] = hi.x; cv.u[3] = hi.y;
                vfrag = cv.v;
            }
            f32x4 o = __builtin_amdgcn_mfma_f32_16x16x32_bf16(vfrag, wfrag, (f32x4){0.f, 0.f, 0.f, 0.f}, 0, 0, 0);
            if constexpr (SUM == 0) {
                if (lam < 12) {
                    int row = baseRow + 12 * n + lam;
                    if (row < totalRows) {
                        uint32_t w0 = (uint32_t)f2bf(o[0]) | ((uint32_t)f2bf(o[1]) << 16);
                        uint32_t w1 = (uint32_t)f2bf(o[2]) | ((uint32_t)f2bf(o[3]) << 16);
                        *(uint2*)(io + (size_t)row * 128 + nt * 16 + 4 * g) = make_uint2(w0, w1);
                    }
                }
            } else {
                #pragma unroll
                for (int r = 0; r < 4; r++) {
                    float v = (lam < 12) ? o[r] : 0.f;
                    v += __shfl_xor(v, 1); v += __shfl_xor(v, 2);
                    v += __shfl_xor(v, 4); v += __shfl_xor(v, 8);
                    o[r] = v;
                }
                if (lam == 0 && (baseRow + 12 * n) < totalRows) {
                    int node = blockIdx.x * 4 + n;
                    *(float4*)(outF + (size_t)node * 128 + nt * 16 + 4 * g) =
                        make_float4(o[0], o[1], o[2], o[3]);
                }
            }
        }
    }
}

// ---------------- conv2: vectorized full-row gather on selected nodes ----------------

__global__ __launch_bounds__(256) void conv2_kernel(
    const unsigned short* __restrict__ emb1, const int* __restrict__ node_idx,
    const int* __restrict__ rs, const int* __restrict__ csr,
    const float* __restrict__ Wlt, const float* __restrict__ Wrt,
    const float* __restrict__ b2, unsigned short* __restrict__ emb2) {
    int bb = blockIdx.x, tid = threadIdx.x;
    int n = node_idx[bb];
    __shared__ float s_mean[1536], s_h[1536];
    int beg = rs[n], end = rs[n + 1];
    if (tid < 192) {
        float acc[8] = {0.f, 0.f, 0.f, 0.f, 0.f, 0.f, 0.f, 0.f};
        for (int e = beg; e < end; e++) {
            int nbr = csr[e];
            bf16x8v v = *(const bf16x8v*)(emb1 + (size_t)nbr * 1536 + tid * 8);
            float f[8]; unpack8(v, f);
            #pragma unroll
            for (int i = 0; i < 8; i++) acc[i] += f[i];
        }
        float inv = 1.0f / fmaxf((float)(end - beg), 1.0f);
        #pragma unroll
        for (int i = 0; i < 8; i++) s_mean[tid * 8 + i] = acc[i] * inv;
    } else {
        for (int c = tid - 192; c < 192; c += 64) {
            bf16x8v v = *(const bf16x8v*)(emb1 + (size_t)n * 1536 + c * 8);
            float f[8]; unpack8(v, f);
            #pragma unroll
            for (int i = 0; i < 8; i++) s_h[c * 8 + i] = f[i];
        }
    }
    __syncthreads();
    int i = tid & 127, th = tid >> 7;
    #pragma unroll
    for (int r = 0; r < 6; r++) {
        int t = r * 2 + th;
        float o = b2[i];
        for (int j = 0; j < 128; j++)
            o += s_mean[t * 128 + j] * Wlt[j * 128 + i] + s_h[t * 128 + j] * Wrt[j * 128 + i];
        emb2[(size_t)bb * 1536 + t * 128 + i] = f2bf(fmaxf(o, 0.0f));
    }
}

// ---------------- MLP head ----------------

__global__ __launch_bounds__(256) void head_kernel(
    const float* __restrict__ embF, const float* __restrict__ apart, const float* __restrict__ fc1Wt,
    const float* __restrict__ fc1b, const float* __restrict__ fc2Wt, const float* __restrict__ fc2b,
    const float* __restrict__ fc3W, const float* __restrict__ fc3b, float* __restrict__ out) {
    int bb = blockIdx.x, tid = threadIdx.x;
    __shared__ float in_s[138], a1[256], a2[128], red[128];
    if (tid < 128) in_s[tid] = embF[(size_t)bb * 128 + tid];
    else if (tid < 138) in_s[tid] = apart[(size_t)bb * 10 + tid - 128];
    __syncthreads();
    float o = fc1b[tid];
    for (int j = 0; j < 138; j++) o += in_s[j] * fc1Wt[j * 256 + tid];
    a1[tid] = o >= 0.f ? o : 0.1f * o;
    __syncthreads();
    if (tid < 128) {
        float o2 = fc2b[tid];
        for (int j = 0; j < 256; j++) o2 += a1[j] * fc2Wt[j * 128 + tid];
        a2[tid] = o2 >= 0.f ? o2 : 0.05f * o2;
    }
    __syncthreads();
    if (tid < 128) red[tid] = a2[tid] * fc3W[tid];
    __syncthreads();
    for (int s = 64; s > 0; s >>= 1) {
        if (tid < s) red[tid] += red[tid + s];
        __syncthreads();
    }
    if (tid == 0) out[bb] = red[0] + fc3b[0];
}

// ---------------- launch ----------------

extern "C" void kernel_launch(void* const* d_in, const int* in_sizes, int n_in,
                              void* d_out, int out_size, void* d_ws, size_t ws_size,
                              hipStream_t stream) {
    const float* x    = (const float*)d_in[0];
    const int* ei     = (const int*)d_in[1];
    const int* nidx   = (const int*)d_in[2];
    const float* apart= (const float*)d_in[3];
    const float* c1Wl = (const float*)d_in[4];
    const float* c1Wr = (const float*)d_in[5];
    const float* c1b  = (const float*)d_in[6];
    const float* c2Wl = (const float*)d_in[7];
    const float* c2Wr = (const float*)d_in[8];
    const float* c2b  = (const float*)d_in[9];
    const float* Wq   = (const float*)d_in[10];
    const float* bq   = (const float*)d_in[11];
    const float* Wk   = (const float*)d_in[12];
    const float* bk   = (const float*)d_in[13];
    const float* Wv   = (const float*)d_in[14];
    const float* bv   = (const float*)d_in[15];
    const float* fc1W = (const float*)d_in[16];
    const float* fc1b = (const float*)d_in[17];
    const float* fc2W = (const float*)d_in[18];
    const float* fc2b = (const float*)d_in[19];
    const float* fc3W = (const float*)d_in[20];
    const float* fc3b = (const float*)d_in[21];

    int N = in_sizes[0] / 144;
    int E = in_sizes[1] / 2;
    int B = in_sizes[2];
    float* out = (float*)d_out;
    char* ws = (char*)d_ws;

    size_t off = 0;
    auto A = [&](size_t bytes) -> void* {
        void* q = ws + off;
        off = (off + bytes + 255) & ~(size_t)255;
        return q;
    };
    unsigned short* emb1 = (unsigned short*)A((size_t)N * 1536 * 2);
    size_t xtBytes = (size_t)N * 144 * 2;
    unsigned short* xTb = (unsigned short*)A(xtBytes);
    unsigned short* emb2;
    if ((size_t)B * 1536 * 2 <= xtBytes) emb2 = xTb;  // alias (xTb dead after conv1)
    else emb2 = (unsigned short*)A((size_t)B * 1536 * 2);
    float* embF  = (float*)A((size_t)B * 128 * 4);
    unsigned short* Bpack = (unsigned short*)A(3 * 16384 * 2);
    float* Wl2t  = (float*)A(16384 * 4);
    float* Wr2t  = (float*)A(16384 * 4);
    float* fc1Wt = (float*)A(138 * 256 * 4);
    float* fc2Wt = (float*)A(256 * 128 * 4);
    int* deg = (int*)A((size_t)N * 4);
    int* rsb = (int*)A((size_t)(N + 1) * 4);
    int* cur = (int*)A((size_t)N * 4);
    int* csr = (int*)A((size_t)E * 4);
    if (off > ws_size) {
        sentinel_kernel<<<(out_size + 255) / 256, 256, 0, stream>>>(out, out_size);
        return;
    }

    (void)hipMemsetAsync(deg, 0, (size_t)N * 4, stream);
    (void)hipMemsetAsync(cur, 0, (size_t)N * 4, stream);

    int eb = (E + 255) / 256;
    transpose_xb_kernel<<<(N + 63) / 64, 256, 0, stream>>>(x, xTb, N);
    deg_kernel<<<eb, 256, 0, stream>>>(ei, deg, E);
    scan_kernel<<<1, 1024, 0, stream>>>(deg, rsb, N);
    fill_kernel<<<eb, 256, 0, stream>>>(ei, rsb, cur, csr, E);

    prep_weights_kernel<<<(150016 + 255) / 256, 256, 0, stream>>>(
        c2Wl, c2Wr, fc1W, fc2W, Wq, Wk, Wv, Wl2t, Wr2t, fc1Wt, fc2Wt, Bpack);

    conv1_kernel<<<N, 256, 0, stream>>>(xTb, rsb, csr, c1Wl, c1Wr, c1b, emb1);

    int rows1 = N * 12;
    mfma_attn_kernel<0><<<(rows1 + 47) / 48, 64, 0, stream>>>(emb1, Bpack, bq, bk, bv, nullptr, rows1);

    conv2_kernel<<<B, 256, 0, stream>>>(emb1, nidx, rsb, csr, Wl2t, Wr2t, c2b, emb2);

    int rows2 = B * 12;
    mfma_attn_kernel<1><<<(rows2 + 47) / 48, 64, 0, stream>>>(emb2, Bpack, bq, bk, bv, embF, rows2);

    head_kernel<<<B, 256, 0, stream>>>(embF, apart, fc1Wt, fc1b, fc2Wt, fc2b, fc3W, fc3b, out);
}